// Round 12
// baseline (350.597 us; speedup 1.0000x reference)
//
#include <hip/hip_runtime.h>
#include <hip/hip_fp16.h>
#include <math.h>

#define N_NODES 100000
#define N_EDGES 1600000
#define N_GRAPHS 64
#define EMB 128
#define HID 64

#define BUCKET_BITS 9
#define BUCKET_SZ   512
#define NB          196   // ceil(N_NODES / 512)
#define EPB         8192  // edges per block in bucket passes
#define CP_BLOCKS   196   // ceil(N_EDGES / 8192) -- count/scatter blocks
#define PROJ_BLOCKS 1563  // ceil(N_NODES / 64)
#define NPB         32    // nodes per gin block (8 per wave)

// ---------------- fp16 packed helpers ----------------

typedef _Float16 half2_t __attribute__((ext_vector_type(2)));

__device__ inline unsigned hadd2u(unsigned a, unsigned b) {
    __half2 ha = __builtin_bit_cast(__half2, a);
    __half2 hb = __builtin_bit_cast(__half2, b);
    return __builtin_bit_cast(unsigned, __hadd2(ha, hb));
}

__device__ inline unsigned relu2(unsigned v) {
    unsigned m = (v >> 15) & 0x00010001u;
    return v & ~(m * 0xFFFFu);
}

__device__ inline float fdot2h(unsigned a, unsigned b, float c) {
#if __has_builtin(__builtin_amdgcn_fdot2)
    half2_t ha = __builtin_bit_cast(half2_t, a);
    half2_t hb = __builtin_bit_cast(half2_t, b);
    return __builtin_amdgcn_fdot2(ha, hb, c, false);
#else
    __half2 ha = __builtin_bit_cast(__half2, a);
    __half2 hb = __builtin_bit_cast(__half2, b);
    float2 fa = __half22float2(ha);
    float2 fb = __half22float2(hb);
    return fmaf(fa.x, fb.x, fmaf(fa.y, fb.y, c));
#endif
}

__device__ inline unsigned pack2(float a, float b) {
    __half2 p = __floats2half2_rn(a, b);
    return __builtin_bit_cast(unsigned, p);
}

// ---------------- block-wide exclusive scan over 256 threads ----------------

__device__ inline int block_scan_excl_256(int v) {
    int t = threadIdx.x;
    int lane = t & 63, wid = t >> 6;
    int incl = v;
    #pragma unroll
    for (int off = 1; off < 64; off <<= 1) {
        int u = __shfl_up(incl, off);
        if (lane >= off) incl += u;
    }
    __shared__ int wsum[4];
    if (lane == 63) wsum[wid] = incl;
    __syncthreads();
    int woff = 0;
    for (int w = 0; w < wid; ++w) woff += wsum[w];
    __syncthreads();
    return woff + incl - v;
}

// ---------------- prep: pack 5 weight mats to fp16 + zero accumulators ----------------
// Wp layout m=0..4: c1_W2, c2_W2, c3_W2, c2_W1, c3_W1 (each 64x64 -> 2048 u32)

__global__ void prep_kernel(const float* __restrict__ w0, const float* __restrict__ w1,
                            const float* __restrict__ w2, const float* __restrict__ w3,
                            const float* __restrict__ w4, unsigned* __restrict__ out,
                            int* __restrict__ bucketCnt, float* __restrict__ pool,
                            float* __restrict__ counts) {
    if (blockIdx.x < 40) {
        int m = blockIdx.x >> 3;
        int i = (blockIdx.x & 7) * 256 + threadIdx.x;
        const float* W = (m == 0) ? w0 : (m == 1) ? w1 : (m == 2) ? w2 : (m == 3) ? w3 : w4;
        int k2 = i >> 6, o = i & 63;
        out[m * 2048 + i] = pack2(W[(2 * k2) * 64 + o], W[(2 * k2 + 1) * 64 + o]);
    } else {
        for (int i = threadIdx.x; i < NB; i += 256) bucketCnt[i] = 0;
        for (int i = threadIdx.x; i < N_GRAPHS * 64; i += 256) pool[i] = 0.0f;
        for (int i = threadIdx.x; i < N_GRAPHS; i += 256) counts[i] = 0.0f;
    }
}

// ---------------- fused: bucket_count (blocks 0..195) + proj128 (blocks 196+) ----------------

__global__ __launch_bounds__(256) void count_proj_kernel(const int* __restrict__ dst,
                                                         int* __restrict__ bucketCnt,
                                                         int* __restrict__ blockBins,
                                                         const float* __restrict__ x,
                                                         const float* __restrict__ W,
                                                         ushort* __restrict__ y) {
    __shared__ int bins[NB];
    if (blockIdx.x < CP_BLOCKS) {
        // ---- bucket histogram over 8192 edges ----
        for (int i = threadIdx.x; i < NB; i += 256) bins[i] = 0;
        __syncthreads();
        int base = blockIdx.x * EPB;
        #pragma unroll 8
        for (int j = 0; j < 32; ++j) {
            int i = base + j * 256 + threadIdx.x;
            if (i < N_EDGES) atomicAdd(&bins[dst[i] >> BUCKET_BITS], 1);
        }
        __syncthreads();
        for (int i = threadIdx.x; i < NB; i += 256) {
            int b = bins[i];
            blockBins[blockIdx.x * NB + i] = b;
            if (b) atomicAdd(&bucketCnt[i], b);
        }
    } else {
        // ---- proj128: y = x @ c1_W1 (fp32 in, fp16 out) ----
        int wid  = threadIdx.x >> 6;
        int lane = threadIdx.x & 63;
        int node = (blockIdx.x - CP_BLOCKS) * 64 + lane;
        bool valid = node < N_NODES;
        const float4* row = reinterpret_cast<const float4*>(x + (size_t)(valid ? node : 0) * EMB);
        int ob = __builtin_amdgcn_readfirstlane(wid * 16);

        float acc[16];
        #pragma unroll
        for (int o = 0; o < 16; ++o) acc[o] = 0.0f;

        #pragma unroll 4
        for (int k4 = 0; k4 < EMB / 4; ++k4) {
            float4 a = row[k4];
            #pragma unroll
            for (int kk = 0; kk < 4; ++kk) {
                int k = k4 * 4 + kk;
                float av = (kk == 0) ? a.x : (kk == 1) ? a.y : (kk == 2) ? a.z : a.w;
                const float* wr = W + k * 64 + ob;   // uniform address -> s_load
                #pragma unroll
                for (int o = 0; o < 16; ++o)
                    acc[o] = fmaf(av, wr[o], acc[o]);
            }
        }

        if (valid) {
            uint4 p0, p1;
            p0.x = pack2(acc[0], acc[1]);   p0.y = pack2(acc[2], acc[3]);
            p0.z = pack2(acc[4], acc[5]);   p0.w = pack2(acc[6], acc[7]);
            p1.x = pack2(acc[8], acc[9]);   p1.y = pack2(acc[10], acc[11]);
            p1.z = pack2(acc[12], acc[13]); p1.w = pack2(acc[14], acc[15]);
            uint4* yr = reinterpret_cast<uint4*>(y + (size_t)node * 64 + ob);
            yr[0] = p0;
            yr[1] = p1;
        }
    }
}

// ---------------- CSR build (uint32-packed entries: dstLocal9 << 17 | src17) ----------------

__global__ void bucket_scan(const int* __restrict__ bucketCnt, int* __restrict__ bucketOff,
                            int* __restrict__ bucketCur, int* __restrict__ row_ptr) {
    int t = threadIdx.x;
    int v = (t < NB) ? bucketCnt[t] : 0;
    int excl = block_scan_excl_256(v);
    if (t < NB) { bucketOff[t] = excl; bucketCur[t] = excl; }
    if (t == 0) { bucketOff[NB] = N_EDGES; row_ptr[N_NODES] = N_EDGES; }
}

__global__ __launch_bounds__(256) void bucket_scatter(const int* __restrict__ src,
                                                      const int* __restrict__ dst,
                                                      const int* __restrict__ blockBins,
                                                      int* __restrict__ bucketCur,
                                                      unsigned* __restrict__ sorted, int e) {
    __shared__ int lbase[NB];
    __shared__ int gbase[NB];
    __shared__ int cur[NB];
    __shared__ unsigned stage[EPB];        // 32 KB
    __shared__ unsigned char stageb[EPB];  // 8 KB

    int t = threadIdx.x;
    int v = (t < NB) ? blockBins[blockIdx.x * NB + t] : 0;
    int excl = block_scan_excl_256(v);
    if (t < NB) {
        lbase[t] = excl;
        cur[t]   = excl;
        gbase[t] = v ? atomicAdd(&bucketCur[t], v) : 0;
    }
    __syncthreads();

    int base = blockIdx.x * EPB;
    #pragma unroll 8
    for (int j = 0; j < 32; ++j) {
        int i = base + j * 256 + threadIdx.x;
        if (i < e) {
            int d = dst[i], s = src[i];
            int b = d >> BUCKET_BITS;
            int p = atomicAdd(&cur[b], 1);
            stage[p]  = ((unsigned)(d & (BUCKET_SZ - 1)) << 17) | (unsigned)s;
            stageb[p] = (unsigned char)b;
        }
    }
    __syncthreads();

    int cnt = min(EPB, e - base);
    for (int idx = threadIdx.x; idx < cnt; idx += 256) {
        int b = stageb[idx];
        sorted[gbase[b] + (idx - lbase[b])] = stage[idx];   // contiguous runs per bucket
    }
}

__global__ __launch_bounds__(256) void bucket_csr(const unsigned* __restrict__ sorted,
                                                  const int* __restrict__ bucketOff,
                                                  int* __restrict__ row_ptr,
                                                  int* __restrict__ col_idx) {
    int b  = blockIdx.x;
    int S  = bucketOff[b];
    int Eb = bucketOff[b + 1];
    int n0 = b << BUCKET_BITS;
    int nNodes = min(BUCKET_SZ, N_NODES - n0);

    __shared__ int cnt[BUCKET_SZ];
    __shared__ int excl[BUCKET_SZ];
    __shared__ int cur[BUCKET_SZ];

    for (int i = threadIdx.x; i < BUCKET_SZ; i += 256) cnt[i] = 0;
    __syncthreads();

    for (int idx = S + threadIdx.x; idx < Eb; idx += 256)
        atomicAdd(&cnt[sorted[idx] >> 17], 1);
    __syncthreads();

    int t = threadIdx.x;
    int v = cnt[2 * t] + cnt[2 * t + 1];
    int pe = block_scan_excl_256(v);
    excl[2 * t]     = pe;
    excl[2 * t + 1] = pe + cnt[2 * t];
    __syncthreads();

    for (int i = threadIdx.x; i < nNodes; i += 256)
        row_ptr[n0 + i] = S + excl[i];
    for (int i = threadIdx.x; i < BUCKET_SZ; i += 256) cur[i] = excl[i];
    __syncthreads();

    for (int idx = S + threadIdx.x; idx < Eb; idx += 256) {
        unsigned ed = sorted[idx];
        int ln = (int)(ed >> 17);
        int slot = S + atomicAdd(&cur[ln], 1);
        col_idx[slot] = (int)(ed & 0x1FFFFu);
    }
}

// ---------------- proj16: y = h16 @ Wp (64 -> 64), dot2 on packed fp16 ----------------

__global__ __launch_bounds__(256) void proj16_kernel(const ushort* __restrict__ h16,
                                                     const unsigned* __restrict__ Wp,
                                                     ushort* __restrict__ y) {
    int wid  = threadIdx.x >> 6;
    int lane = threadIdx.x & 63;
    int node = blockIdx.x * 64 + lane;
    bool valid = node < N_NODES;
    const uint4* row4 = reinterpret_cast<const uint4*>(h16 + (size_t)(valid ? node : 0) * 64);
    int ob = __builtin_amdgcn_readfirstlane(wid * 16);

    uint4 r[8];
    #pragma unroll
    for (int i = 0; i < 8; ++i) r[i] = row4[i];
    const unsigned* ru = reinterpret_cast<const unsigned*>(r);

    float acc[16];
    #pragma unroll
    for (int o = 0; o < 16; ++o) acc[o] = 0.0f;

    #pragma unroll 8
    for (int k2 = 0; k2 < 32; ++k2) {
        unsigned rp = ru[k2];
        const unsigned* wr = Wp + k2 * 64 + ob;   // uniform address -> s_load
        #pragma unroll
        for (int o = 0; o < 16; ++o)
            acc[o] = fdot2h(rp, wr[o], acc[o]);
    }

    if (valid) {
        uint4 p0, p1;
        p0.x = pack2(acc[0], acc[1]);   p0.y = pack2(acc[2], acc[3]);
        p0.z = pack2(acc[4], acc[5]);   p0.w = pack2(acc[6], acc[7]);
        p1.x = pack2(acc[8], acc[9]);   p1.y = pack2(acc[10], acc[11]);
        p1.z = pack2(acc[12], acc[13]); p1.w = pack2(acc[14], acc[15]);
        uint4* yr = reinterpret_cast<uint4*>(y + (size_t)node * 64 + ob);
        yr[0] = p0;
        yr[1] = p1;
    }
}

// ---------------- fused layer (round-7 inner loop, proven; 8 nodes/wave) ----------------
// lane = (e4 = lane>>4, c16 = lane&15). 16 lanes x uint2 (8B, 4 halves) = one
// 128B fp16 row per group; 4 rows per load instruction, 16 rows in flight.
// 36 VGPR -> 8 waves/SIMD: TLP does the latency hiding (reg pipelining regressed
// twice: R8 fusion, R9 A/B buffers). DO NOT add register pipelines here.
// MODE 1: h16 = out (relu if RELU). MODE 2: accumulate pool/counts (no relu, no store).

template <int MODE, int RELU>
__global__ __launch_bounds__(256) void gin_layer(const ushort* __restrict__ y,
                                                 const int* __restrict__ row_ptr,
                                                 const int* __restrict__ col_idx,
                                                 const float* __restrict__ b1,
                                                 const unsigned* __restrict__ W2p,
                                                 const float* __restrict__ b2,
                                                 ushort* __restrict__ hout16,
                                                 const int* __restrict__ batch,
                                                 float* __restrict__ pool,
                                                 float* __restrict__ counts) {
    __shared__ unsigned sW2p[32 * 64];   // packed half2 [k2][o], 8 KB
    __shared__ unsigned stp[4][32];      // packed st per wave

    {
        const uint4* a = reinterpret_cast<const uint4*>(W2p);
        uint4* dd = reinterpret_cast<uint4*>(sW2p);
        dd[threadIdx.x]       = a[threadIdx.x];
        dd[threadIdx.x + 256] = a[threadIdx.x + 256];
    }
    __syncthreads();

    int wid  = threadIdx.x >> 6;
    int lane = threadIdx.x & 63;
    int e4   = lane >> 4;       // edge sub-group 0..3
    int c16  = lane & 15;       // channel chunk (4 halves) 0..15
    int nb8  = blockIdx.x * NPB + wid * 8;

    const uint2* yp = reinterpret_cast<const uint2*>(y);  // row stride = 16 uint2
    float4 b1f = reinterpret_cast<const float4*>(b1)[c16];
    unsigned bp0 = pack2(b1f.x, b1f.y);
    unsigned bp1 = pack2(b1f.z, b1f.w);
    float b2v = b2[lane];

    int bvals = 0, curg = 0;
    float pacc = 0.0f, pcnt = 0.0f;
    if (MODE == 2) {
        bvals = batch[nb8 + (lane & 7)];
        curg  = __shfl(bvals, 0);
    }

    #pragma unroll 1
    for (int t = 0; t < 8; ++t) {
        int node = nb8 + t;

        int start = row_ptr[node];
        int end   = row_ptr[node + 1];

        unsigned a0 = 0u, a1 = 0u;
        if (e4 == 0) {
            uint2 s = yp[(size_t)node * 16 + c16];   // self term
            a0 = s.x; a1 = s.y;
        }

        int base = start;
        // main: 16 edges per iteration, 4 row-loads in flight per lane-group
        for (; base + 16 <= end; base += 16) {
            int i0 = col_idx[base + e4];
            int i1 = col_idx[base + 4 + e4];
            int i2 = col_idx[base + 8 + e4];
            int i3 = col_idx[base + 12 + e4];
            uint2 u0 = yp[(size_t)i0 * 16 + c16];
            uint2 u1 = yp[(size_t)i1 * 16 + c16];
            uint2 u2 = yp[(size_t)i2 * 16 + c16];
            uint2 u3 = yp[(size_t)i3 * 16 + c16];
            a0 = hadd2u(a0, u0.x); a1 = hadd2u(a1, u0.y);
            a0 = hadd2u(a0, u1.x); a1 = hadd2u(a1, u1.y);
            a0 = hadd2u(a0, u2.x); a1 = hadd2u(a1, u2.y);
            a0 = hadd2u(a0, u3.x); a1 = hadd2u(a1, u3.y);
        }
        // tail: rem < 16, straight-line predicated (loads stay in flight)
        {
            uint2 z = make_uint2(0u, 0u);
            uint2 u0 = z, u1 = z, u2 = z, u3 = z;
            if (base + e4 < end)      u0 = yp[(size_t)col_idx[base + e4] * 16 + c16];
            if (base + 4 + e4 < end)  u1 = yp[(size_t)col_idx[base + 4 + e4] * 16 + c16];
            if (base + 8 + e4 < end)  u2 = yp[(size_t)col_idx[base + 8 + e4] * 16 + c16];
            if (base + 12 + e4 < end) u3 = yp[(size_t)col_idx[base + 12 + e4] * 16 + c16];
            a0 = hadd2u(a0, u0.x); a1 = hadd2u(a1, u0.y);
            a0 = hadd2u(a0, u1.x); a1 = hadd2u(a1, u1.y);
            a0 = hadd2u(a0, u2.x); a1 = hadd2u(a1, u2.y);
            a0 = hadd2u(a0, u3.x); a1 = hadd2u(a1, u3.y);
        }

        // reduce across the 4 edge groups (lanes differing in bits 4,5)
        #pragma unroll
        for (int m = 16; m <= 32; m <<= 1) {
            a0 = hadd2u(a0, (unsigned)__shfl_xor((int)a0, m));
            a1 = hadd2u(a1, (unsigned)__shfl_xor((int)a1, m));
        }

        // bias + relu in packed fp16; publish to wave-private st
        a0 = relu2(hadd2u(a0, bp0));
        a1 = relu2(hadd2u(a1, bp1));
        if (e4 == 0)
            reinterpret_cast<uint2*>(stp[wid])[c16] = make_uint2(a0, a1);

        // GEMM2: u[lane] = b2[lane] + sum_k2 dot2(st2[k2], W2p[k2][lane])
        float u = b2v;
        const uint4* sp = reinterpret_cast<const uint4*>(stp[wid]);
        #pragma unroll
        for (int j = 0; j < 8; ++j) {
            uint4 q = sp[j];
            u = fdot2h(q.x, sW2p[(4 * j + 0) * 64 + lane], u);
            u = fdot2h(q.y, sW2p[(4 * j + 1) * 64 + lane], u);
            u = fdot2h(q.z, sW2p[(4 * j + 2) * 64 + lane], u);
            u = fdot2h(q.w, sW2p[(4 * j + 3) * 64 + lane], u);
        }
        if (MODE == 1) {
            if (RELU) u = fmaxf(u, 0.0f);
            hout16[(size_t)node * 64 + lane] = __half_as_ushort(__float2half_rn(u));
        } else {
            int g = __shfl(bvals, t);        // wave-uniform graph id
            if (g != curg) {                 // rare flush
                atomicAdd(&pool[curg * 64 + lane], pacc);
                if (lane == 0) atomicAdd(&counts[curg], pcnt);
                curg = g; pacc = 0.0f; pcnt = 0.0f;
            }
            pacc += u;
            pcnt += 1.0f;
        }
    }

    if (MODE == 2) {
        atomicAdd(&pool[curg * 64 + lane], pacc);
        if (lane == 0) atomicAdd(&counts[curg], pcnt);
    }
}

// ---------------- head: pooled @ fc1 + b, @ pred + b, sigmoid ----------------

__global__ void head_kernel(const float* __restrict__ pool, const float* __restrict__ counts,
                            const float* __restrict__ fc1_W, const float* __restrict__ fc1_b,
                            const float* __restrict__ pred_W, const float* __restrict__ pred_b,
                            float* __restrict__ out) {
    int g = blockIdx.x;
    int t = threadIdx.x;
    float s = 0.0f;
    if (t < 32) {
        float cnt = fmaxf(counts[g], 1.0f);
        float inv = 1.0f / cnt;
        float f = fc1_b[t];
        #pragma unroll
        for (int k = 0; k < 64; ++k)
            f = fmaf(pool[g * 64 + k] * inv, fc1_W[k * 32 + t], f);
        s = f * pred_W[t];
    }
    #pragma unroll
    for (int off = 32; off > 0; off >>= 1) s += __shfl_down(s, off);
    if (t == 0) out[g] = 1.0f / (1.0f + expf(-(s + pred_b[0])));
}

// ---------------- launch ----------------

extern "C" void kernel_launch(void* const* d_in, const int* in_sizes, int n_in,
                              void* d_out, int out_size, void* d_ws, size_t ws_size,
                              hipStream_t stream) {
    const float* x      = (const float*)d_in[0];
    const int*   e_src  = (const int*)d_in[1];
    const int*   e_dst  = ((const int*)d_in[1]) + N_EDGES;
    const int*   batch  = (const int*)d_in[2];
    const float* c1_W1 = (const float*)d_in[3];
    const float* c1_b1 = (const float*)d_in[4];
    const float* c1_W2 = (const float*)d_in[5];
    const float* c1_b2 = (const float*)d_in[6];
    const float* c2_W1 = (const float*)d_in[7];
    const float* c2_b1 = (const float*)d_in[8];
    const float* c2_W2 = (const float*)d_in[9];
    const float* c2_b2 = (const float*)d_in[10];
    const float* c3_W1 = (const float*)d_in[11];
    const float* c3_b1 = (const float*)d_in[12];
    const float* c3_W2 = (const float*)d_in[13];
    const float* c3_b2 = (const float*)d_in[14];
    const float* fc1_W = (const float*)d_in[15];
    const float* fc1_b = (const float*)d_in[16];
    const float* predW = (const float*)d_in[17];
    const float* predb = (const float*)d_in[18];
    float* out = (float*)d_out;

    char* ws = (char*)d_ws;
    size_t off = 0;
    auto carve = [&](size_t bytes) {
        char* p = ws + off;
        off += (bytes + 255) & ~(size_t)255;
        return p;
    };
    ushort*   y        = (ushort*)carve((size_t)N_NODES * 64 * 2);    // 12.8 MB
    ushort*   h16      = (ushort*)carve((size_t)N_NODES * 64 * 2);    // 12.8 MB
    unsigned* sorted   = (unsigned*)carve((size_t)N_EDGES * 4);       // 6.4 MB (own buffer:
                                                                      // y is written before scatter now)
    int*      row_ptr  = (int*)carve(((size_t)N_NODES + 1) * 4);
    int*      col_idx  = (int*)carve((size_t)N_EDGES * 4);
    int*      bucketCnt = (int*)carve(NB * 4);
    int*      bucketOff = (int*)carve((NB + 1) * 4);
    int*      bucketCur = (int*)carve(NB * 4);
    int*      blockBins = (int*)carve((size_t)CP_BLOCKS * NB * 4);    // 154 KB
    float*    pool     = (float*)carve(N_GRAPHS * 64 * 4);
    float*    counts   = (float*)carve(N_GRAPHS * 4);
    unsigned* Wp       = (unsigned*)carve(5 * 2048 * 4);
    (void)ws_size; (void)n_in; (void)in_sizes; (void)out_size;

    const int GIN_BLOCKS = N_NODES / NPB;   // 3125 (32 nodes/block)

    // 1. prep: pack weights + zero accumulators
    prep_kernel<<<41, 256, 0, stream>>>(c1_W2, c2_W2, c3_W2, c2_W1, c3_W1, Wp,
                                        bucketCnt, pool, counts);

    // 2. fused bucket histogram + layer-1 projection (independent work)
    count_proj_kernel<<<CP_BLOCKS + PROJ_BLOCKS, 256, 0, stream>>>(
        e_dst, bucketCnt, blockBins, x, c1_W1, y);

    // 3-5. CSR build
    bucket_scan<<<1, 256, 0, stream>>>(bucketCnt, bucketOff, bucketCur, row_ptr);
    bucket_scatter<<<CP_BLOCKS, 256, 0, stream>>>(e_src, e_dst, blockBins, bucketCur,
                                                  sorted, N_EDGES);
    bucket_csr<<<NB, 256, 0, stream>>>(sorted, bucketOff, row_ptr, col_idx);

    // 6-9. layers 1-2 (h in fp16 end-to-end; proj via dot2 on packed W1)
    gin_layer<1, 1><<<GIN_BLOCKS, 256, 0, stream>>>(y, row_ptr, col_idx, c1_b1,
                                                    Wp + 0 * 2048, c1_b2, h16,
                                                    nullptr, nullptr, nullptr);
    proj16_kernel<<<PROJ_BLOCKS, 256, 0, stream>>>(h16, Wp + 3 * 2048, y);
    gin_layer<1, 1><<<GIN_BLOCKS, 256, 0, stream>>>(y, row_ptr, col_idx, c2_b1,
                                                    Wp + 1 * 2048, c2_b2, h16,
                                                    nullptr, nullptr, nullptr);
    proj16_kernel<<<PROJ_BLOCKS, 256, 0, stream>>>(h16, Wp + 4 * 2048, y);

    // 10. layer 3 with fused mean-pool accumulation (no h materialization)
    gin_layer<2, 0><<<GIN_BLOCKS, 256, 0, stream>>>(y, row_ptr, col_idx, c3_b1,
                                                    Wp + 2 * 2048, c3_b2, nullptr,
                                                    batch, pool, counts);

    // 11. head
    head_kernel<<<N_GRAPHS, 64, 0, stream>>>(pool, counts, fc1_W, fc1_b, predW, predb, out);
}

// Round 13
// 300.706 us; speedup vs baseline: 1.1659x; 1.1659x over previous
//
#include <hip/hip_runtime.h>
#include <hip/hip_fp16.h>
#include <math.h>

#define N_NODES 100000
#define N_EDGES 1600000
#define N_GRAPHS 64
#define EMB 128
#define HID 64

#define BUCKET_BITS 9
#define BUCKET_SZ   512
#define NB          196   // ceil(N_NODES / 512)
#define EPB         8192  // edges per block in bucket passes
#define CP_BLOCKS   196   // ceil(N_EDGES / 8192) -- count/scatter blocks
#define PROJ_BLOCKS 1563  // ceil(N_NODES / 64)
#define NPB         32    // nodes per gin block (8 per wave)

// ---------------- fp16 packed helpers ----------------

typedef _Float16 half2_t __attribute__((ext_vector_type(2)));

__device__ inline unsigned hadd2u(unsigned a, unsigned b) {
    __half2 ha = __builtin_bit_cast(__half2, a);
    __half2 hb = __builtin_bit_cast(__half2, b);
    return __builtin_bit_cast(unsigned, __hadd2(ha, hb));
}

__device__ inline unsigned relu2(unsigned v) {
    unsigned m = (v >> 15) & 0x00010001u;
    return v & ~(m * 0xFFFFu);
}

__device__ inline float fdot2h(unsigned a, unsigned b, float c) {
#if __has_builtin(__builtin_amdgcn_fdot2)
    half2_t ha = __builtin_bit_cast(half2_t, a);
    half2_t hb = __builtin_bit_cast(half2_t, b);
    return __builtin_amdgcn_fdot2(ha, hb, c, false);
#else
    __half2 ha = __builtin_bit_cast(__half2, a);
    __half2 hb = __builtin_bit_cast(__half2, b);
    float2 fa = __half22float2(ha);
    float2 fb = __half22float2(hb);
    return fmaf(fa.x, fb.x, fmaf(fa.y, fb.y, c));
#endif
}

__device__ inline unsigned pack2(float a, float b) {
    __half2 p = __floats2half2_rn(a, b);
    return __builtin_bit_cast(unsigned, p);
}

// ---------------- block-wide exclusive scan over 256 threads ----------------

__device__ inline int block_scan_excl_256(int v) {
    int t = threadIdx.x;
    int lane = t & 63, wid = t >> 6;
    int incl = v;
    #pragma unroll
    for (int off = 1; off < 64; off <<= 1) {
        int u = __shfl_up(incl, off);
        if (lane >= off) incl += u;
    }
    __shared__ int wsum[4];
    if (lane == 63) wsum[wid] = incl;
    __syncthreads();
    int woff = 0;
    for (int w = 0; w < wid; ++w) woff += wsum[w];
    __syncthreads();
    return woff + incl - v;
}

// ---------------- prep: pack 5 weight mats to fp16 + zero accumulators ----------------
// Wp layout m=0..4: c1_W2, c2_W2, c3_W2, c2_W1, c3_W1 (each 64x64 -> 2048 u32)

__global__ void prep_kernel(const float* __restrict__ w0, const float* __restrict__ w1,
                            const float* __restrict__ w2, const float* __restrict__ w3,
                            const float* __restrict__ w4, unsigned* __restrict__ out,
                            int* __restrict__ bucketCnt, float* __restrict__ pool,
                            float* __restrict__ counts) {
    if (blockIdx.x < 40) {
        int m = blockIdx.x >> 3;
        int i = (blockIdx.x & 7) * 256 + threadIdx.x;
        const float* W = (m == 0) ? w0 : (m == 1) ? w1 : (m == 2) ? w2 : (m == 3) ? w3 : w4;
        int k2 = i >> 6, o = i & 63;
        out[m * 2048 + i] = pack2(W[(2 * k2) * 64 + o], W[(2 * k2 + 1) * 64 + o]);
    } else {
        for (int i = threadIdx.x; i < NB; i += 256) bucketCnt[i] = 0;
        for (int i = threadIdx.x; i < N_GRAPHS * 64; i += 256) pool[i] = 0.0f;
        for (int i = threadIdx.x; i < N_GRAPHS; i += 256) counts[i] = 0.0f;
    }
}

// ---------------- fused: bucket_count (blocks 0..195) + proj128 (blocks 196+) ----------------

__global__ __launch_bounds__(256) void count_proj_kernel(const int* __restrict__ dst,
                                                         int* __restrict__ bucketCnt,
                                                         int* __restrict__ blockBins,
                                                         const float* __restrict__ x,
                                                         const float* __restrict__ W,
                                                         ushort* __restrict__ y) {
    __shared__ int bins[NB];
    if (blockIdx.x < CP_BLOCKS) {
        // ---- bucket histogram over 8192 edges ----
        for (int i = threadIdx.x; i < NB; i += 256) bins[i] = 0;
        __syncthreads();
        int base = blockIdx.x * EPB;
        #pragma unroll 8
        for (int j = 0; j < 32; ++j) {
            int i = base + j * 256 + threadIdx.x;
            if (i < N_EDGES) atomicAdd(&bins[dst[i] >> BUCKET_BITS], 1);
        }
        __syncthreads();
        for (int i = threadIdx.x; i < NB; i += 256) {
            int b = bins[i];
            blockBins[blockIdx.x * NB + i] = b;
            if (b) atomicAdd(&bucketCnt[i], b);
        }
    } else {
        // ---- proj128: y = x @ c1_W1 (fp32 in, fp16 out) ----
        int wid  = threadIdx.x >> 6;
        int lane = threadIdx.x & 63;
        int node = (blockIdx.x - CP_BLOCKS) * 64 + lane;
        bool valid = node < N_NODES;
        const float4* row = reinterpret_cast<const float4*>(x + (size_t)(valid ? node : 0) * EMB);
        int ob = __builtin_amdgcn_readfirstlane(wid * 16);

        float acc[16];
        #pragma unroll
        for (int o = 0; o < 16; ++o) acc[o] = 0.0f;

        #pragma unroll 4
        for (int k4 = 0; k4 < EMB / 4; ++k4) {
            float4 a = row[k4];
            #pragma unroll
            for (int kk = 0; kk < 4; ++kk) {
                int k = k4 * 4 + kk;
                float av = (kk == 0) ? a.x : (kk == 1) ? a.y : (kk == 2) ? a.z : a.w;
                const float* wr = W + k * 64 + ob;   // uniform address -> s_load
                #pragma unroll
                for (int o = 0; o < 16; ++o)
                    acc[o] = fmaf(av, wr[o], acc[o]);
            }
        }

        if (valid) {
            uint4 p0, p1;
            p0.x = pack2(acc[0], acc[1]);   p0.y = pack2(acc[2], acc[3]);
            p0.z = pack2(acc[4], acc[5]);   p0.w = pack2(acc[6], acc[7]);
            p1.x = pack2(acc[8], acc[9]);   p1.y = pack2(acc[10], acc[11]);
            p1.z = pack2(acc[12], acc[13]); p1.w = pack2(acc[14], acc[15]);
            uint4* yr = reinterpret_cast<uint4*>(y + (size_t)node * 64 + ob);
            yr[0] = p0;
            yr[1] = p1;
        }
    }
}

// ---------------- CSR build (uint32-packed entries: dstLocal9 << 17 | src17) ----------------

__global__ void bucket_scan(const int* __restrict__ bucketCnt, int* __restrict__ bucketOff,
                            int* __restrict__ bucketCur, int* __restrict__ row_ptr) {
    int t = threadIdx.x;
    int v = (t < NB) ? bucketCnt[t] : 0;
    int excl = block_scan_excl_256(v);
    if (t < NB) { bucketOff[t] = excl; bucketCur[t] = excl; }
    if (t == 0) { bucketOff[NB] = N_EDGES; row_ptr[N_NODES] = N_EDGES; }
}

__global__ __launch_bounds__(256) void bucket_scatter(const int* __restrict__ src,
                                                      const int* __restrict__ dst,
                                                      const int* __restrict__ blockBins,
                                                      int* __restrict__ bucketCur,
                                                      unsigned* __restrict__ sorted, int e) {
    __shared__ int lbase[NB];
    __shared__ int gbase[NB];
    __shared__ int cur[NB];
    __shared__ unsigned stage[EPB];        // 32 KB
    __shared__ unsigned char stageb[EPB];  // 8 KB

    int t = threadIdx.x;
    int v = (t < NB) ? blockBins[blockIdx.x * NB + t] : 0;
    int excl = block_scan_excl_256(v);
    if (t < NB) {
        lbase[t] = excl;
        cur[t]   = excl;
        gbase[t] = v ? atomicAdd(&bucketCur[t], v) : 0;
    }
    __syncthreads();

    int base = blockIdx.x * EPB;
    #pragma unroll 8
    for (int j = 0; j < 32; ++j) {
        int i = base + j * 256 + threadIdx.x;
        if (i < e) {
            int d = dst[i], s = src[i];
            int b = d >> BUCKET_BITS;
            int p = atomicAdd(&cur[b], 1);
            stage[p]  = ((unsigned)(d & (BUCKET_SZ - 1)) << 17) | (unsigned)s;
            stageb[p] = (unsigned char)b;
        }
    }
    __syncthreads();

    int cnt = min(EPB, e - base);
    for (int idx = threadIdx.x; idx < cnt; idx += 256) {
        int b = stageb[idx];
        sorted[gbase[b] + (idx - lbase[b])] = stage[idx];   // contiguous runs per bucket
    }
}

__global__ __launch_bounds__(256) void bucket_csr(const unsigned* __restrict__ sorted,
                                                  const int* __restrict__ bucketOff,
                                                  int* __restrict__ row_ptr,
                                                  int* __restrict__ col_idx) {
    int b  = blockIdx.x;
    int S  = bucketOff[b];
    int Eb = bucketOff[b + 1];
    int n0 = b << BUCKET_BITS;
    int nNodes = min(BUCKET_SZ, N_NODES - n0);

    __shared__ int cnt[BUCKET_SZ];
    __shared__ int excl[BUCKET_SZ];
    __shared__ int cur[BUCKET_SZ];

    for (int i = threadIdx.x; i < BUCKET_SZ; i += 256) cnt[i] = 0;
    __syncthreads();

    for (int idx = S + threadIdx.x; idx < Eb; idx += 256)
        atomicAdd(&cnt[sorted[idx] >> 17], 1);
    __syncthreads();

    int t = threadIdx.x;
    int v = cnt[2 * t] + cnt[2 * t + 1];
    int pe = block_scan_excl_256(v);
    excl[2 * t]     = pe;
    excl[2 * t + 1] = pe + cnt[2 * t];
    __syncthreads();

    for (int i = threadIdx.x; i < nNodes; i += 256)
        row_ptr[n0 + i] = S + excl[i];
    for (int i = threadIdx.x; i < BUCKET_SZ; i += 256) cur[i] = excl[i];
    __syncthreads();

    for (int idx = S + threadIdx.x; idx < Eb; idx += 256) {
        unsigned ed = sorted[idx];
        int ln = (int)(ed >> 17);
        int slot = S + atomicAdd(&cur[ln], 1);
        col_idx[slot] = (int)(ed & 0x1FFFFu);
    }
}

// ---------------- proj16: y = h16 @ Wp (64 -> 64), dot2 on packed fp16 ----------------

__global__ __launch_bounds__(256) void proj16_kernel(const ushort* __restrict__ h16,
                                                     const unsigned* __restrict__ Wp,
                                                     ushort* __restrict__ y) {
    int wid  = threadIdx.x >> 6;
    int lane = threadIdx.x & 63;
    int node = blockIdx.x * 64 + lane;
    bool valid = node < N_NODES;
    const uint4* row4 = reinterpret_cast<const uint4*>(h16 + (size_t)(valid ? node : 0) * 64);
    int ob = __builtin_amdgcn_readfirstlane(wid * 16);

    uint4 r[8];
    #pragma unroll
    for (int i = 0; i < 8; ++i) r[i] = row4[i];
    const unsigned* ru = reinterpret_cast<const unsigned*>(r);

    float acc[16];
    #pragma unroll
    for (int o = 0; o < 16; ++o) acc[o] = 0.0f;

    #pragma unroll 8
    for (int k2 = 0; k2 < 32; ++k2) {
        unsigned rp = ru[k2];
        const unsigned* wr = Wp + k2 * 64 + ob;   // uniform address -> s_load
        #pragma unroll
        for (int o = 0; o < 16; ++o)
            acc[o] = fdot2h(rp, wr[o], acc[o]);
    }

    if (valid) {
        uint4 p0, p1;
        p0.x = pack2(acc[0], acc[1]);   p0.y = pack2(acc[2], acc[3]);
        p0.z = pack2(acc[4], acc[5]);   p0.w = pack2(acc[6], acc[7]);
        p1.x = pack2(acc[8], acc[9]);   p1.y = pack2(acc[10], acc[11]);
        p1.z = pack2(acc[12], acc[13]); p1.w = pack2(acc[14], acc[15]);
        uint4* yr = reinterpret_cast<uint4*>(y + (size_t)node * 64 + ob);
        yr[0] = p0;
        yr[1] = p1;
    }
}

// ---------------- fused layer (round-7/11 inner loop, proven; 8 nodes/wave) ----------------
// lane = (e4 = lane>>4, c16 = lane&15). 16 lanes x uint2 (8B, 4 halves) = one
// 128B fp16 row per group; 4 rows per load instruction, 16 rows in flight.
// 36 VGPR -> 8 waves/SIMD: TLP does the latency hiding. Regressions on record:
// R8 (fused next-proj), R9 (reg A/B pipeline), R12 (fused pool, MODE-2 state).
// DO NOT add per-node state or extra template variants to this kernel.
// Always writes fp16 h; RELU selects the output activation.

template <int RELU>
__global__ __launch_bounds__(256) void gin_layer(const ushort* __restrict__ y,
                                                 const int* __restrict__ row_ptr,
                                                 const int* __restrict__ col_idx,
                                                 const float* __restrict__ b1,
                                                 const unsigned* __restrict__ W2p,
                                                 const float* __restrict__ b2,
                                                 ushort* __restrict__ hout16) {
    __shared__ unsigned sW2p[32 * 64];   // packed half2 [k2][o], 8 KB
    __shared__ unsigned stp[4][32];      // packed st per wave

    {
        const uint4* a = reinterpret_cast<const uint4*>(W2p);
        uint4* dd = reinterpret_cast<uint4*>(sW2p);
        dd[threadIdx.x]       = a[threadIdx.x];
        dd[threadIdx.x + 256] = a[threadIdx.x + 256];
    }
    __syncthreads();

    int wid  = threadIdx.x >> 6;
    int lane = threadIdx.x & 63;
    int e4   = lane >> 4;       // edge sub-group 0..3
    int c16  = lane & 15;       // channel chunk (4 halves) 0..15

    const uint2* yp = reinterpret_cast<const uint2*>(y);  // row stride = 16 uint2
    float4 b1f = reinterpret_cast<const float4*>(b1)[c16];
    unsigned bp0 = pack2(b1f.x, b1f.y);
    unsigned bp1 = pack2(b1f.z, b1f.w);
    float b2v = b2[lane];

    #pragma unroll 1
    for (int t = 0; t < 8; ++t) {
        int node = blockIdx.x * NPB + wid * 8 + t;

        int start = row_ptr[node];
        int end   = row_ptr[node + 1];

        unsigned a0 = 0u, a1 = 0u;
        if (e4 == 0) {
            uint2 s = yp[(size_t)node * 16 + c16];   // self term
            a0 = s.x; a1 = s.y;
        }

        int base = start;
        // main: 16 edges per iteration, 4 row-loads in flight per lane-group
        for (; base + 16 <= end; base += 16) {
            int i0 = col_idx[base + e4];
            int i1 = col_idx[base + 4 + e4];
            int i2 = col_idx[base + 8 + e4];
            int i3 = col_idx[base + 12 + e4];
            uint2 u0 = yp[(size_t)i0 * 16 + c16];
            uint2 u1 = yp[(size_t)i1 * 16 + c16];
            uint2 u2 = yp[(size_t)i2 * 16 + c16];
            uint2 u3 = yp[(size_t)i3 * 16 + c16];
            a0 = hadd2u(a0, u0.x); a1 = hadd2u(a1, u0.y);
            a0 = hadd2u(a0, u1.x); a1 = hadd2u(a1, u1.y);
            a0 = hadd2u(a0, u2.x); a1 = hadd2u(a1, u2.y);
            a0 = hadd2u(a0, u3.x); a1 = hadd2u(a1, u3.y);
        }
        // tail: rem < 16, straight-line predicated (loads stay in flight)
        {
            uint2 z = make_uint2(0u, 0u);
            uint2 u0 = z, u1 = z, u2 = z, u3 = z;
            if (base + e4 < end)      u0 = yp[(size_t)col_idx[base + e4] * 16 + c16];
            if (base + 4 + e4 < end)  u1 = yp[(size_t)col_idx[base + 4 + e4] * 16 + c16];
            if (base + 8 + e4 < end)  u2 = yp[(size_t)col_idx[base + 8 + e4] * 16 + c16];
            if (base + 12 + e4 < end) u3 = yp[(size_t)col_idx[base + 12 + e4] * 16 + c16];
            a0 = hadd2u(a0, u0.x); a1 = hadd2u(a1, u0.y);
            a0 = hadd2u(a0, u1.x); a1 = hadd2u(a1, u1.y);
            a0 = hadd2u(a0, u2.x); a1 = hadd2u(a1, u2.y);
            a0 = hadd2u(a0, u3.x); a1 = hadd2u(a1, u3.y);
        }

        // reduce across the 4 edge groups (lanes differing in bits 4,5)
        #pragma unroll
        for (int m = 16; m <= 32; m <<= 1) {
            a0 = hadd2u(a0, (unsigned)__shfl_xor((int)a0, m));
            a1 = hadd2u(a1, (unsigned)__shfl_xor((int)a1, m));
        }

        // bias + relu in packed fp16; publish to wave-private st
        a0 = relu2(hadd2u(a0, bp0));
        a1 = relu2(hadd2u(a1, bp1));
        if (e4 == 0)
            reinterpret_cast<uint2*>(stp[wid])[c16] = make_uint2(a0, a1);

        // GEMM2: u[lane] = b2[lane] + sum_k2 dot2(st2[k2], W2p[k2][lane])
        float u = b2v;
        const uint4* sp = reinterpret_cast<const uint4*>(stp[wid]);
        #pragma unroll
        for (int j = 0; j < 8; ++j) {
            uint4 q = sp[j];
            u = fdot2h(q.x, sW2p[(4 * j + 0) * 64 + lane], u);
            u = fdot2h(q.y, sW2p[(4 * j + 1) * 64 + lane], u);
            u = fdot2h(q.z, sW2p[(4 * j + 2) * 64 + lane], u);
            u = fdot2h(q.w, sW2p[(4 * j + 3) * 64 + lane], u);
        }
        if (RELU) u = fmaxf(u, 0.0f);
        hout16[(size_t)node * 64 + lane] = __half_as_ushort(__float2half_rn(u));
    }
}

// ---------------- pooling: segment mean over fp16 h (batch is sorted) ----------------

__global__ __launch_bounds__(256) void pool_kernel(const ushort* __restrict__ h,
                                                   const int* __restrict__ batch,
                                                   float* __restrict__ pool,
                                                   float* __restrict__ counts, int n) {
    int gwave = (blockIdx.x * 256 + threadIdx.x) >> 6;
    int lane  = threadIdx.x & 63;
    int s = gwave * 64;
    if (s >= n) return;
    int nhere = min(64, n - s);

    int bv = (s + lane < n) ? batch[s + lane] : -1;
    int cur = __shfl(bv, 0);
    float acc = 0.0f, cnt = 0.0f;

    #pragma unroll 1
    for (int i0 = 0; i0 < 64; i0 += 8) {
        float v[8];
        #pragma unroll
        for (int j = 0; j < 8; ++j) {
            int i = i0 + j;
            v[j] = (i < nhere)
                 ? __half2float(__ushort_as_half(h[(size_t)(s + i) * 64 + lane]))
                 : 0.0f;
        }
        #pragma unroll
        for (int j = 0; j < 8; ++j) {
            int i = i0 + j;
            if (i < nhere) {
                int g = __shfl(bv, i);
                if (g != cur) {   // wave-uniform, rare
                    atomicAdd(&pool[cur * 64 + lane], acc);
                    if (lane == 0) atomicAdd(&counts[cur], cnt);
                    cur = g; acc = 0.0f; cnt = 0.0f;
                }
                acc += v[j];
                cnt += 1.0f;
            }
        }
    }
    atomicAdd(&pool[cur * 64 + lane], acc);
    if (lane == 0) atomicAdd(&counts[cur], cnt);
}

// ---------------- head: pooled @ fc1 + b, @ pred + b, sigmoid ----------------

__global__ void head_kernel(const float* __restrict__ pool, const float* __restrict__ counts,
                            const float* __restrict__ fc1_W, const float* __restrict__ fc1_b,
                            const float* __restrict__ pred_W, const float* __restrict__ pred_b,
                            float* __restrict__ out) {
    int g = blockIdx.x;
    int t = threadIdx.x;
    float s = 0.0f;
    if (t < 32) {
        float cnt = fmaxf(counts[g], 1.0f);
        float inv = 1.0f / cnt;
        float f = fc1_b[t];
        #pragma unroll
        for (int k = 0; k < 64; ++k)
            f = fmaf(pool[g * 64 + k] * inv, fc1_W[k * 32 + t], f);
        s = f * pred_W[t];
    }
    #pragma unroll
    for (int off = 32; off > 0; off >>= 1) s += __shfl_down(s, off);
    if (t == 0) out[g] = 1.0f / (1.0f + expf(-(s + pred_b[0])));
}

// ---------------- launch ----------------

extern "C" void kernel_launch(void* const* d_in, const int* in_sizes, int n_in,
                              void* d_out, int out_size, void* d_ws, size_t ws_size,
                              hipStream_t stream) {
    const float* x      = (const float*)d_in[0];
    const int*   e_src  = (const int*)d_in[1];
    const int*   e_dst  = ((const int*)d_in[1]) + N_EDGES;
    const int*   batch  = (const int*)d_in[2];
    const float* c1_W1 = (const float*)d_in[3];
    const float* c1_b1 = (const float*)d_in[4];
    const float* c1_W2 = (const float*)d_in[5];
    const float* c1_b2 = (const float*)d_in[6];
    const float* c2_W1 = (const float*)d_in[7];
    const float* c2_b1 = (const float*)d_in[8];
    const float* c2_W2 = (const float*)d_in[9];
    const float* c2_b2 = (const float*)d_in[10];
    const float* c3_W1 = (const float*)d_in[11];
    const float* c3_b1 = (const float*)d_in[12];
    const float* c3_W2 = (const float*)d_in[13];
    const float* c3_b2 = (const float*)d_in[14];
    const float* fc1_W = (const float*)d_in[15];
    const float* fc1_b = (const float*)d_in[16];
    const float* predW = (const float*)d_in[17];
    const float* predb = (const float*)d_in[18];
    float* out = (float*)d_out;

    char* ws = (char*)d_ws;
    size_t off = 0;
    auto carve = [&](size_t bytes) {
        char* p = ws + off;
        off += (bytes + 255) & ~(size_t)255;
        return p;
    };
    ushort*   y        = (ushort*)carve((size_t)N_NODES * 64 * 2);    // 12.8 MB
    ushort*   h16      = (ushort*)carve((size_t)N_NODES * 64 * 2);    // 12.8 MB
    unsigned* sorted   = (unsigned*)carve((size_t)N_EDGES * 4);       // 6.4 MB
    int*      row_ptr  = (int*)carve(((size_t)N_NODES + 1) * 4);
    int*      col_idx  = (int*)carve((size_t)N_EDGES * 4);
    int*      bucketCnt = (int*)carve(NB * 4);
    int*      bucketOff = (int*)carve((NB + 1) * 4);
    int*      bucketCur = (int*)carve(NB * 4);
    int*      blockBins = (int*)carve((size_t)CP_BLOCKS * NB * 4);    // 154 KB
    float*    pool     = (float*)carve(N_GRAPHS * 64 * 4);
    float*    counts   = (float*)carve(N_GRAPHS * 4);
    unsigned* Wp       = (unsigned*)carve(5 * 2048 * 4);
    (void)ws_size; (void)n_in; (void)in_sizes; (void)out_size;

    const int GIN_BLOCKS  = N_NODES / NPB;          // 3125 (32 nodes/block)
    const int POOL_BLOCKS = (N_NODES + 255) / 256;  // 391

    // 1. prep: pack weights + zero accumulators
    prep_kernel<<<41, 256, 0, stream>>>(c1_W2, c2_W2, c3_W2, c2_W1, c3_W1, Wp,
                                        bucketCnt, pool, counts);

    // 2. fused bucket histogram + layer-1 projection (independent work)
    count_proj_kernel<<<CP_BLOCKS + PROJ_BLOCKS, 256, 0, stream>>>(
        e_dst, bucketCnt, blockBins, x, c1_W1, y);

    // 3-5. CSR build
    bucket_scan<<<1, 256, 0, stream>>>(bucketCnt, bucketOff, bucketCur, row_ptr);
    bucket_scatter<<<CP_BLOCKS, 256, 0, stream>>>(e_src, e_dst, blockBins, bucketCur,
                                                  sorted, N_EDGES);
    bucket_csr<<<NB, 256, 0, stream>>>(sorted, bucketOff, row_ptr, col_idx);

    // 6-10. layers (h fp16 end-to-end; proj via dot2 on packed W1)
    gin_layer<1><<<GIN_BLOCKS, 256, 0, stream>>>(y, row_ptr, col_idx, c1_b1,
                                                 Wp + 0 * 2048, c1_b2, h16);
    proj16_kernel<<<PROJ_BLOCKS, 256, 0, stream>>>(h16, Wp + 3 * 2048, y);
    gin_layer<1><<<GIN_BLOCKS, 256, 0, stream>>>(y, row_ptr, col_idx, c2_b1,
                                                 Wp + 1 * 2048, c2_b2, h16);
    proj16_kernel<<<PROJ_BLOCKS, 256, 0, stream>>>(h16, Wp + 4 * 2048, y);
    gin_layer<0><<<GIN_BLOCKS, 256, 0, stream>>>(y, row_ptr, col_idx, c3_b1,
                                                 Wp + 2 * 2048, c3_b2, h16);

    // 11-12. pool + head
    pool_kernel<<<POOL_BLOCKS, 256, 0, stream>>>(h16, batch, pool, counts, N_NODES);
    head_kernel<<<N_GRAPHS, 64, 0, stream>>>(pool, counts, fc1_W, fc1_b, predW, predb, out);
}

// Round 14
// 280.606 us; speedup vs baseline: 1.2494x; 1.0716x over previous
//
#include <hip/hip_runtime.h>
#include <hip/hip_fp16.h>
#include <math.h>

#define N_NODES 100000
#define N_EDGES 1600000
#define N_GRAPHS 64
#define EMB 128
#define HID 64

#define BUCKET_BITS 9
#define BUCKET_SZ   512
#define NB          196   // ceil(N_NODES / 512)
#define EPB         8192  // edges per block in bucket passes
#define CP_BLOCKS   196   // ceil(N_EDGES / 8192) -- count/scatter blocks
#define PROJ_BLOCKS 1563  // ceil(N_NODES / 64)
#define NPB         32    // nodes per gin block (8 per wave)

// ---------------- fp16 packed helpers ----------------

typedef _Float16 half2_t __attribute__((ext_vector_type(2)));

__device__ inline unsigned hadd2u(unsigned a, unsigned b) {
    __half2 ha = __builtin_bit_cast(__half2, a);
    __half2 hb = __builtin_bit_cast(__half2, b);
    return __builtin_bit_cast(unsigned, __hadd2(ha, hb));
}

__device__ inline unsigned relu2(unsigned v) {
    unsigned m = (v >> 15) & 0x00010001u;
    return v & ~(m * 0xFFFFu);
}

__device__ inline float fdot2h(unsigned a, unsigned b, float c) {
#if __has_builtin(__builtin_amdgcn_fdot2)
    half2_t ha = __builtin_bit_cast(half2_t, a);
    half2_t hb = __builtin_bit_cast(half2_t, b);
    return __builtin_amdgcn_fdot2(ha, hb, c, false);
#else
    __half2 ha = __builtin_bit_cast(__half2, a);
    __half2 hb = __builtin_bit_cast(__half2, b);
    float2 fa = __half22float2(ha);
    float2 fb = __half22float2(hb);
    return fmaf(fa.x, fb.x, fmaf(fa.y, fb.y, c));
#endif
}

__device__ inline unsigned pack2(float a, float b) {
    __half2 p = __floats2half2_rn(a, b);
    return __builtin_bit_cast(unsigned, p);
}

// ---------------- block-wide exclusive scan over 256 threads ----------------

__device__ inline int block_scan_excl_256(int v) {
    int t = threadIdx.x;
    int lane = t & 63, wid = t >> 6;
    int incl = v;
    #pragma unroll
    for (int off = 1; off < 64; off <<= 1) {
        int u = __shfl_up(incl, off);
        if (lane >= off) incl += u;
    }
    __shared__ int wsum[4];
    if (lane == 63) wsum[wid] = incl;
    __syncthreads();
    int woff = 0;
    for (int w = 0; w < wid; ++w) woff += wsum[w];
    __syncthreads();
    return woff + incl - v;
}

// ---------------- prep: pack 5 weight mats to fp16 + zero accumulators ----------------
// Wp layout m=0..4: c1_W2, c2_W2, c3_W2, c2_W1, c3_W1 (each 64x64 -> 2048 u32)

__global__ void prep_kernel(const float* __restrict__ w0, const float* __restrict__ w1,
                            const float* __restrict__ w2, const float* __restrict__ w3,
                            const float* __restrict__ w4, unsigned* __restrict__ out,
                            int* __restrict__ bucketCnt, float* __restrict__ pool,
                            float* __restrict__ counts) {
    if (blockIdx.x < 40) {
        int m = blockIdx.x >> 3;
        int i = (blockIdx.x & 7) * 256 + threadIdx.x;
        const float* W = (m == 0) ? w0 : (m == 1) ? w1 : (m == 2) ? w2 : (m == 3) ? w3 : w4;
        int k2 = i >> 6, o = i & 63;
        out[m * 2048 + i] = pack2(W[(2 * k2) * 64 + o], W[(2 * k2 + 1) * 64 + o]);
    } else {
        for (int i = threadIdx.x; i < NB; i += 256) bucketCnt[i] = 0;
        for (int i = threadIdx.x; i < N_GRAPHS * 64; i += 256) pool[i] = 0.0f;
        for (int i = threadIdx.x; i < N_GRAPHS; i += 256) counts[i] = 0.0f;
    }
}

// ---------------- fused: bucket_count (blocks 0..195) + proj128 (blocks 196+) ----------------

__global__ __launch_bounds__(256) void count_proj_kernel(const int* __restrict__ dst,
                                                         int* __restrict__ bucketCnt,
                                                         int* __restrict__ blockBins,
                                                         const float* __restrict__ x,
                                                         const float* __restrict__ W,
                                                         ushort* __restrict__ y) {
    __shared__ int bins[NB];
    if (blockIdx.x < CP_BLOCKS) {
        // ---- bucket histogram over 8192 edges ----
        for (int i = threadIdx.x; i < NB; i += 256) bins[i] = 0;
        __syncthreads();
        int base = blockIdx.x * EPB;
        #pragma unroll 8
        for (int j = 0; j < 32; ++j) {
            int i = base + j * 256 + threadIdx.x;
            if (i < N_EDGES) atomicAdd(&bins[dst[i] >> BUCKET_BITS], 1);
        }
        __syncthreads();
        for (int i = threadIdx.x; i < NB; i += 256) {
            int b = bins[i];
            blockBins[blockIdx.x * NB + i] = b;
            if (b) atomicAdd(&bucketCnt[i], b);
        }
    } else {
        // ---- proj128: y = x @ c1_W1 (fp32 in, fp16 out) ----
        int wid  = threadIdx.x >> 6;
        int lane = threadIdx.x & 63;
        int node = (blockIdx.x - CP_BLOCKS) * 64 + lane;
        bool valid = node < N_NODES;
        const float4* row = reinterpret_cast<const float4*>(x + (size_t)(valid ? node : 0) * EMB);
        int ob = __builtin_amdgcn_readfirstlane(wid * 16);

        float acc[16];
        #pragma unroll
        for (int o = 0; o < 16; ++o) acc[o] = 0.0f;

        #pragma unroll 4
        for (int k4 = 0; k4 < EMB / 4; ++k4) {
            float4 a = row[k4];
            #pragma unroll
            for (int kk = 0; kk < 4; ++kk) {
                int k = k4 * 4 + kk;
                float av = (kk == 0) ? a.x : (kk == 1) ? a.y : (kk == 2) ? a.z : a.w;
                const float* wr = W + k * 64 + ob;   // uniform address -> s_load
                #pragma unroll
                for (int o = 0; o < 16; ++o)
                    acc[o] = fmaf(av, wr[o], acc[o]);
            }
        }

        if (valid) {
            uint4 p0, p1;
            p0.x = pack2(acc[0], acc[1]);   p0.y = pack2(acc[2], acc[3]);
            p0.z = pack2(acc[4], acc[5]);   p0.w = pack2(acc[6], acc[7]);
            p1.x = pack2(acc[8], acc[9]);   p1.y = pack2(acc[10], acc[11]);
            p1.z = pack2(acc[12], acc[13]); p1.w = pack2(acc[14], acc[15]);
            uint4* yr = reinterpret_cast<uint4*>(y + (size_t)node * 64 + ob);
            yr[0] = p0;
            yr[1] = p1;
        }
    }
}

// ---------------- CSR build (uint32-packed entries: dstLocal9 << 17 | src17) ----------------

__global__ void bucket_scan(const int* __restrict__ bucketCnt, int* __restrict__ bucketOff,
                            int* __restrict__ bucketCur, int* __restrict__ row_ptr) {
    int t = threadIdx.x;
    int v = (t < NB) ? bucketCnt[t] : 0;
    int excl = block_scan_excl_256(v);
    if (t < NB) { bucketOff[t] = excl; bucketCur[t] = excl; }
    if (t == 0) { bucketOff[NB] = N_EDGES; row_ptr[N_NODES] = N_EDGES; }
}

__global__ __launch_bounds__(256) void bucket_scatter(const int* __restrict__ src,
                                                      const int* __restrict__ dst,
                                                      const int* __restrict__ blockBins,
                                                      int* __restrict__ bucketCur,
                                                      unsigned* __restrict__ sorted, int e) {
    __shared__ int lbase[NB];
    __shared__ int gbase[NB];
    __shared__ int cur[NB];
    __shared__ unsigned stage[EPB];        // 32 KB
    __shared__ unsigned char stageb[EPB];  // 8 KB

    int t = threadIdx.x;
    int v = (t < NB) ? blockBins[blockIdx.x * NB + t] : 0;
    int excl = block_scan_excl_256(v);
    if (t < NB) {
        lbase[t] = excl;
        cur[t]   = excl;
        gbase[t] = v ? atomicAdd(&bucketCur[t], v) : 0;
    }
    __syncthreads();

    int base = blockIdx.x * EPB;
    #pragma unroll 8
    for (int j = 0; j < 32; ++j) {
        int i = base + j * 256 + threadIdx.x;
        if (i < e) {
            int d = dst[i], s = src[i];
            int b = d >> BUCKET_BITS;
            int p = atomicAdd(&cur[b], 1);
            stage[p]  = ((unsigned)(d & (BUCKET_SZ - 1)) << 17) | (unsigned)s;
            stageb[p] = (unsigned char)b;
        }
    }
    __syncthreads();

    int cnt = min(EPB, e - base);
    for (int idx = threadIdx.x; idx < cnt; idx += 256) {
        int b = stageb[idx];
        sorted[gbase[b] + (idx - lbase[b])] = stage[idx];   // contiguous runs per bucket
    }
}

__global__ __launch_bounds__(256) void bucket_csr(const unsigned* __restrict__ sorted,
                                                  const int* __restrict__ bucketOff,
                                                  int* __restrict__ row_ptr,
                                                  int* __restrict__ col_idx) {
    int b  = blockIdx.x;
    int S  = bucketOff[b];
    int Eb = bucketOff[b + 1];
    int n0 = b << BUCKET_BITS;
    int nNodes = min(BUCKET_SZ, N_NODES - n0);

    __shared__ int cnt[BUCKET_SZ];
    __shared__ int excl[BUCKET_SZ];
    __shared__ int cur[BUCKET_SZ];

    for (int i = threadIdx.x; i < BUCKET_SZ; i += 256) cnt[i] = 0;
    __syncthreads();

    for (int idx = S + threadIdx.x; idx < Eb; idx += 256)
        atomicAdd(&cnt[sorted[idx] >> 17], 1);
    __syncthreads();

    int t = threadIdx.x;
    int v = cnt[2 * t] + cnt[2 * t + 1];
    int pe = block_scan_excl_256(v);
    excl[2 * t]     = pe;
    excl[2 * t + 1] = pe + cnt[2 * t];
    __syncthreads();

    for (int i = threadIdx.x; i < nNodes; i += 256)
        row_ptr[n0 + i] = S + excl[i];
    for (int i = threadIdx.x; i < BUCKET_SZ; i += 256) cur[i] = excl[i];
    __syncthreads();

    for (int idx = S + threadIdx.x; idx < Eb; idx += 256) {
        unsigned ed = sorted[idx];
        int ln = (int)(ed >> 17);
        int slot = S + atomicAdd(&cur[ln], 1);
        col_idx[slot] = (int)(ed & 0x1FFFFu);
    }
}

// ---------------- proj16: y = h16 @ Wp (64 -> 64), dot2 on packed fp16 ----------------
// STREAMING row loads (R13 post-mortem): loading all 8 uint4 up-front forced the
// compiler (28 VGPR) to evict and re-load the row inside the dot loop -> 25-50us.
// One uint4 per iteration, consumed immediately (the shape the fp32 project
// proved fast): live set = 1 uint4 + acc[16], no reloads.

__global__ __launch_bounds__(256) void proj16_kernel(const ushort* __restrict__ h16,
                                                     const unsigned* __restrict__ Wp,
                                                     ushort* __restrict__ y) {
    int wid  = threadIdx.x >> 6;
    int lane = threadIdx.x & 63;
    int node = blockIdx.x * 64 + lane;
    bool valid = node < N_NODES;
    const uint4* row4 = reinterpret_cast<const uint4*>(h16 + (size_t)(valid ? node : 0) * 64);
    int ob = __builtin_amdgcn_readfirstlane(wid * 16);

    float acc[16];
    #pragma unroll
    for (int o = 0; o < 16; ++o) acc[o] = 0.0f;

    #pragma unroll 2
    for (int i = 0; i < 8; ++i) {
        uint4 rv = row4[i];
        #pragma unroll
        for (int q = 0; q < 4; ++q) {
            int k2 = i * 4 + q;
            unsigned rp = (q == 0) ? rv.x : (q == 1) ? rv.y : (q == 2) ? rv.z : rv.w;
            const unsigned* wr = Wp + k2 * 64 + ob;   // uniform address -> s_load
            #pragma unroll
            for (int o = 0; o < 16; ++o)
                acc[o] = fdot2h(rp, wr[o], acc[o]);
        }
    }

    if (valid) {
        uint4 p0, p1;
        p0.x = pack2(acc[0], acc[1]);   p0.y = pack2(acc[2], acc[3]);
        p0.z = pack2(acc[4], acc[5]);   p0.w = pack2(acc[6], acc[7]);
        p1.x = pack2(acc[8], acc[9]);   p1.y = pack2(acc[10], acc[11]);
        p1.z = pack2(acc[12], acc[13]); p1.w = pack2(acc[14], acc[15]);
        uint4* yr = reinterpret_cast<uint4*>(y + (size_t)node * 64 + ob);
        yr[0] = p0;
        yr[1] = p1;
    }
}

// ---------------- fused layer (round-7/11 inner loop, proven; 8 nodes/wave) ----------------
// lane = (e4 = lane>>4, c16 = lane&15). 16 lanes x uint2 (8B, 4 halves) = one
// 128B fp16 row per group; 4 rows per load instruction, 16 rows in flight.
// 36 VGPR -> 8 waves/SIMD: TLP does the latency hiding. Regressions on record:
// R8 (fused next-proj), R9 (reg A/B pipeline), R12 (fused pool, MODE-2 state).
// DO NOT add per-node state or extra template variants to this kernel.
// Always writes fp16 h; RELU selects the output activation.

template <int RELU>
__global__ __launch_bounds__(256) void gin_layer(const ushort* __restrict__ y,
                                                 const int* __restrict__ row_ptr,
                                                 const int* __restrict__ col_idx,
                                                 const float* __restrict__ b1,
                                                 const unsigned* __restrict__ W2p,
                                                 const float* __restrict__ b2,
                                                 ushort* __restrict__ hout16) {
    __shared__ unsigned sW2p[32 * 64];   // packed half2 [k2][o], 8 KB
    __shared__ unsigned stp[4][32];      // packed st per wave

    {
        const uint4* a = reinterpret_cast<const uint4*>(W2p);
        uint4* dd = reinterpret_cast<uint4*>(sW2p);
        dd[threadIdx.x]       = a[threadIdx.x];
        dd[threadIdx.x + 256] = a[threadIdx.x + 256];
    }
    __syncthreads();

    int wid  = threadIdx.x >> 6;
    int lane = threadIdx.x & 63;
    int e4   = lane >> 4;       // edge sub-group 0..3
    int c16  = lane & 15;       // channel chunk (4 halves) 0..15

    const uint2* yp = reinterpret_cast<const uint2*>(y);  // row stride = 16 uint2
    float4 b1f = reinterpret_cast<const float4*>(b1)[c16];
    unsigned bp0 = pack2(b1f.x, b1f.y);
    unsigned bp1 = pack2(b1f.z, b1f.w);
    float b2v = b2[lane];

    #pragma unroll 1
    for (int t = 0; t < 8; ++t) {
        int node = blockIdx.x * NPB + wid * 8 + t;

        int start = row_ptr[node];
        int end   = row_ptr[node + 1];

        unsigned a0 = 0u, a1 = 0u;
        if (e4 == 0) {
            uint2 s = yp[(size_t)node * 16 + c16];   // self term
            a0 = s.x; a1 = s.y;
        }

        int base = start;
        // main: 16 edges per iteration, 4 row-loads in flight per lane-group
        for (; base + 16 <= end; base += 16) {
            int i0 = col_idx[base + e4];
            int i1 = col_idx[base + 4 + e4];
            int i2 = col_idx[base + 8 + e4];
            int i3 = col_idx[base + 12 + e4];
            uint2 u0 = yp[(size_t)i0 * 16 + c16];
            uint2 u1 = yp[(size_t)i1 * 16 + c16];
            uint2 u2 = yp[(size_t)i2 * 16 + c16];
            uint2 u3 = yp[(size_t)i3 * 16 + c16];
            a0 = hadd2u(a0, u0.x); a1 = hadd2u(a1, u0.y);
            a0 = hadd2u(a0, u1.x); a1 = hadd2u(a1, u1.y);
            a0 = hadd2u(a0, u2.x); a1 = hadd2u(a1, u2.y);
            a0 = hadd2u(a0, u3.x); a1 = hadd2u(a1, u3.y);
        }
        // tail: rem < 16, straight-line predicated (loads stay in flight)
        {
            uint2 z = make_uint2(0u, 0u);
            uint2 u0 = z, u1 = z, u2 = z, u3 = z;
            if (base + e4 < end)      u0 = yp[(size_t)col_idx[base + e4] * 16 + c16];
            if (base + 4 + e4 < end)  u1 = yp[(size_t)col_idx[base + 4 + e4] * 16 + c16];
            if (base + 8 + e4 < end)  u2 = yp[(size_t)col_idx[base + 8 + e4] * 16 + c16];
            if (base + 12 + e4 < end) u3 = yp[(size_t)col_idx[base + 12 + e4] * 16 + c16];
            a0 = hadd2u(a0, u0.x); a1 = hadd2u(a1, u0.y);
            a0 = hadd2u(a0, u1.x); a1 = hadd2u(a1, u1.y);
            a0 = hadd2u(a0, u2.x); a1 = hadd2u(a1, u2.y);
            a0 = hadd2u(a0, u3.x); a1 = hadd2u(a1, u3.y);
        }

        // reduce across the 4 edge groups (lanes differing in bits 4,5)
        #pragma unroll
        for (int m = 16; m <= 32; m <<= 1) {
            a0 = hadd2u(a0, (unsigned)__shfl_xor((int)a0, m));
            a1 = hadd2u(a1, (unsigned)__shfl_xor((int)a1, m));
        }

        // bias + relu in packed fp16; publish to wave-private st
        a0 = relu2(hadd2u(a0, bp0));
        a1 = relu2(hadd2u(a1, bp1));
        if (e4 == 0)
            reinterpret_cast<uint2*>(stp[wid])[c16] = make_uint2(a0, a1);

        // GEMM2: u[lane] = b2[lane] + sum_k2 dot2(st2[k2], W2p[k2][lane])
        float u = b2v;
        const uint4* sp = reinterpret_cast<const uint4*>(stp[wid]);
        #pragma unroll
        for (int j = 0; j < 8; ++j) {
            uint4 q = sp[j];
            u = fdot2h(q.x, sW2p[(4 * j + 0) * 64 + lane], u);
            u = fdot2h(q.y, sW2p[(4 * j + 1) * 64 + lane], u);
            u = fdot2h(q.z, sW2p[(4 * j + 2) * 64 + lane], u);
            u = fdot2h(q.w, sW2p[(4 * j + 3) * 64 + lane], u);
        }
        if (RELU) u = fmaxf(u, 0.0f);
        hout16[(size_t)node * 64 + lane] = __half_as_ushort(__float2half_rn(u));
    }
}

// ---------------- pooling: segment mean over fp16 h (batch is sorted) ----------------

__global__ __launch_bounds__(256) void pool_kernel(const ushort* __restrict__ h,
                                                   const int* __restrict__ batch,
                                                   float* __restrict__ pool,
                                                   float* __restrict__ counts, int n) {
    int gwave = (blockIdx.x * 256 + threadIdx.x) >> 6;
    int lane  = threadIdx.x & 63;
    int s = gwave * 64;
    if (s >= n) return;
    int nhere = min(64, n - s);

    int bv = (s + lane < n) ? batch[s + lane] : -1;
    int cur = __shfl(bv, 0);
    float acc = 0.0f, cnt = 0.0f;

    #pragma unroll 1
    for (int i0 = 0; i0 < 64; i0 += 8) {
        float v[8];
        #pragma unroll
        for (int j = 0; j < 8; ++j) {
            int i = i0 + j;
            v[j] = (i < nhere)
                 ? __half2float(__ushort_as_half(h[(size_t)(s + i) * 64 + lane]))
                 : 0.0f;
        }
        #pragma unroll
        for (int j = 0; j < 8; ++j) {
            int i = i0 + j;
            if (i < nhere) {
                int g = __shfl(bv, i);
                if (g != cur) {   // wave-uniform, rare
                    atomicAdd(&pool[cur * 64 + lane], acc);
                    if (lane == 0) atomicAdd(&counts[cur], cnt);
                    cur = g; acc = 0.0f; cnt = 0.0f;
                }
                acc += v[j];
                cnt += 1.0f;
            }
        }
    }
    atomicAdd(&pool[cur * 64 + lane], acc);
    if (lane == 0) atomicAdd(&counts[cur], cnt);
}

// ---------------- head: pooled @ fc1 + b, @ pred + b, sigmoid ----------------

__global__ void head_kernel(const float* __restrict__ pool, const float* __restrict__ counts,
                            const float* __restrict__ fc1_W, const float* __restrict__ fc1_b,
                            const float* __restrict__ pred_W, const float* __restrict__ pred_b,
                            float* __restrict__ out) {
    int g = blockIdx.x;
    int t = threadIdx.x;
    float s = 0.0f;
    if (t < 32) {
        float cnt = fmaxf(counts[g], 1.0f);
        float inv = 1.0f / cnt;
        float f = fc1_b[t];
        #pragma unroll
        for (int k = 0; k < 64; ++k)
            f = fmaf(pool[g * 64 + k] * inv, fc1_W[k * 32 + t], f);
        s = f * pred_W[t];
    }
    #pragma unroll
    for (int off = 32; off > 0; off >>= 1) s += __shfl_down(s, off);
    if (t == 0) out[g] = 1.0f / (1.0f + expf(-(s + pred_b[0])));
}

// ---------------- launch ----------------

extern "C" void kernel_launch(void* const* d_in, const int* in_sizes, int n_in,
                              void* d_out, int out_size, void* d_ws, size_t ws_size,
                              hipStream_t stream) {
    const float* x      = (const float*)d_in[0];
    const int*   e_src  = (const int*)d_in[1];
    const int*   e_dst  = ((const int*)d_in[1]) + N_EDGES;
    const int*   batch  = (const int*)d_in[2];
    const float* c1_W1 = (const float*)d_in[3];
    const float* c1_b1 = (const float*)d_in[4];
    const float* c1_W2 = (const float*)d_in[5];
    const float* c1_b2 = (const float*)d_in[6];
    const float* c2_W1 = (const float*)d_in[7];
    const float* c2_b1 = (const float*)d_in[8];
    const float* c2_W2 = (const float*)d_in[9];
    const float* c2_b2 = (const float*)d_in[10];
    const float* c3_W1 = (const float*)d_in[11];
    const float* c3_b1 = (const float*)d_in[12];
    const float* c3_W2 = (const float*)d_in[13];
    const float* c3_b2 = (const float*)d_in[14];
    const float* fc1_W = (const float*)d_in[15];
    const float* fc1_b = (const float*)d_in[16];
    const float* predW = (const float*)d_in[17];
    const float* predb = (const float*)d_in[18];
    float* out = (float*)d_out;

    char* ws = (char*)d_ws;
    size_t off = 0;
    auto carve = [&](size_t bytes) {
        char* p = ws + off;
        off += (bytes + 255) & ~(size_t)255;
        return p;
    };
    ushort*   y        = (ushort*)carve((size_t)N_NODES * 64 * 2);    // 12.8 MB
    ushort*   h16      = (ushort*)carve((size_t)N_NODES * 64 * 2);    // 12.8 MB
    unsigned* sorted   = (unsigned*)carve((size_t)N_EDGES * 4);       // 6.4 MB
    int*      row_ptr  = (int*)carve(((size_t)N_NODES + 1) * 4);
    int*      col_idx  = (int*)carve((size_t)N_EDGES * 4);
    int*      bucketCnt = (int*)carve(NB * 4);
    int*      bucketOff = (int*)carve((NB + 1) * 4);
    int*      bucketCur = (int*)carve(NB * 4);
    int*      blockBins = (int*)carve((size_t)CP_BLOCKS * NB * 4);    // 154 KB
    float*    pool     = (float*)carve(N_GRAPHS * 64 * 4);
    float*    counts   = (float*)carve(N_GRAPHS * 4);
    unsigned* Wp       = (unsigned*)carve(5 * 2048 * 4);
    (void)ws_size; (void)n_in; (void)in_sizes; (void)out_size;

    const int GIN_BLOCKS  = N_NODES / NPB;          // 3125 (32 nodes/block)
    const int POOL_BLOCKS = (N_NODES + 255) / 256;  // 391

    // 1. prep: pack weights + zero accumulators
    prep_kernel<<<41, 256, 0, stream>>>(c1_W2, c2_W2, c3_W2, c2_W1, c3_W1, Wp,
                                        bucketCnt, pool, counts);

    // 2. fused bucket histogram + layer-1 projection (independent work)
    count_proj_kernel<<<CP_BLOCKS + PROJ_BLOCKS, 256, 0, stream>>>(
        e_dst, bucketCnt, blockBins, x, c1_W1, y);

    // 3-5. CSR build
    bucket_scan<<<1, 256, 0, stream>>>(bucketCnt, bucketOff, bucketCur, row_ptr);
    bucket_scatter<<<CP_BLOCKS, 256, 0, stream>>>(e_src, e_dst, blockBins, bucketCur,
                                                  sorted, N_EDGES);
    bucket_csr<<<NB, 256, 0, stream>>>(sorted, bucketOff, row_ptr, col_idx);

    // 6-10. layers (h fp16 end-to-end; proj via dot2 on packed W1)
    gin_layer<1><<<GIN_BLOCKS, 256, 0, stream>>>(y, row_ptr, col_idx, c1_b1,
                                                 Wp + 0 * 2048, c1_b2, h16);
    proj16_kernel<<<PROJ_BLOCKS, 256, 0, stream>>>(h16, Wp + 3 * 2048, y);
    gin_layer<1><<<GIN_BLOCKS, 256, 0, stream>>>(y, row_ptr, col_idx, c2_b1,
                                                 Wp + 1 * 2048, c2_b2, h16);
    proj16_kernel<<<PROJ_BLOCKS, 256, 0, stream>>>(h16, Wp + 4 * 2048, y);
    gin_layer<0><<<GIN_BLOCKS, 256, 0, stream>>>(y, row_ptr, col_idx, c3_b1,
                                                 Wp + 2 * 2048, c3_b2, h16);

    // 11-12. pool + head
    pool_kernel<<<POOL_BLOCKS, 256, 0, stream>>>(h16, batch, pool, counts, N_NODES);
    head_kernel<<<N_GRAPHS, 64, 0, stream>>>(pool, counts, fc1_W, fc1_b, predW, predb, out);
}